// Round 1
// baseline (1442.953 us; speedup 1.0000x reference)
//
#include <hip/hip_runtime.h>

// LowRankRNN: h' = (1-a)h + a*(tanh(h) @ J^T + xp),  J = m n^T (rank 2)
// Phase 1: xp = x @ I^T  (fp32 tiled GEMM, M=65536 N=512 K=128) -> written into d_out
// Phase 2: per-batch sequential scan, 1 wave/batch, h in registers,
//          rank-2 feedback via two DPP wave-reductions, in-place overwrite of d_out.

#define ALPHA 0.1f

// ---------------------------------------------------------------- GEMM ----
#define BM 64
#define BN 64
#define BKK 32
#define LDT 72  // padded LDS row (floats), 16B-aligned groups

__global__ __launch_bounds__(256)
void xproj_gemm(const float* __restrict__ X, const float* __restrict__ Iw,
                float* __restrict__ C) {
  __shared__ float As[BKK * LDT];  // As[k][m]
  __shared__ float Bs[BKK * LDT];  // Bs[k][n]
  const int id = threadIdx.x;
  const int tx = id & 15;   // col group (4 cols)
  const int ty = id >> 4;   // row group (4 rows)
  const int kk = id & 31;   // staging k
  const int mg = id >> 5;   // staging row-group of 8
  const int m0 = blockIdx.x * BM;
  const int n0 = blockIdx.y * BN;

  float acc[4][4] = {};

  for (int k0 = 0; k0 < 128; k0 += BKK) {
    // ---- stage A (x) : rows m0+mg*8+j, col k0+kk -> As[kk][mg*8+j]
    {
      const float* ga = X + (size_t)(m0 + mg * 8) * 128 + k0 + kk;
      float a0 = ga[0 * 128], a1 = ga[1 * 128], a2 = ga[2 * 128], a3 = ga[3 * 128];
      float a4 = ga[4 * 128], a5 = ga[5 * 128], a6 = ga[6 * 128], a7 = ga[7 * 128];
      float4* wa = (float4*)&As[kk * LDT + mg * 8];
      wa[0] = make_float4(a0, a1, a2, a3);
      wa[1] = make_float4(a4, a5, a6, a7);
      const float* gb = Iw + (size_t)(n0 + mg * 8) * 128 + k0 + kk;
      float b0 = gb[0 * 128], b1 = gb[1 * 128], b2 = gb[2 * 128], b3 = gb[3 * 128];
      float b4 = gb[4 * 128], b5 = gb[5 * 128], b6 = gb[6 * 128], b7 = gb[7 * 128];
      float4* wb = (float4*)&Bs[kk * LDT + mg * 8];
      wb[0] = make_float4(b0, b1, b2, b3);
      wb[1] = make_float4(b4, b5, b6, b7);
    }
    __syncthreads();
#pragma unroll
    for (int kb = 0; kb < BKK; ++kb) {
      float4 a = *(const float4*)&As[kb * LDT + ty * 4];
      float4 b = *(const float4*)&Bs[kb * LDT + tx * 4];
      float av[4] = {a.x, a.y, a.z, a.w};
      float bv[4] = {b.x, b.y, b.z, b.w};
#pragma unroll
      for (int i = 0; i < 4; ++i)
#pragma unroll
        for (int j = 0; j < 4; ++j) acc[i][j] = fmaf(av[i], bv[j], acc[i][j]);
    }
    __syncthreads();
  }

#pragma unroll
  for (int i = 0; i < 4; ++i) {
    float4 o = make_float4(acc[i][0], acc[i][1], acc[i][2], acc[i][3]);
    *(float4*)&C[(size_t)(m0 + ty * 4 + i) * 512 + n0 + tx * 4] = o;
  }
}

// ---------------------------------------------------------------- scan ----
// DPP full-wave sum: after the 6 steps lane 63 holds the total.
#define DPP_STEP(v, ctrl)                                                     \
  ((v) + __int_as_float(__builtin_amdgcn_update_dpp(                          \
             0, __float_as_int(v), (ctrl), 0xf, 0xf, true)))

__device__ __forceinline__ float wave_sum63(float v) {
  v = DPP_STEP(v, 0x111);  // row_shr:1
  v = DPP_STEP(v, 0x112);  // row_shr:2
  v = DPP_STEP(v, 0x114);  // row_shr:4
  v = DPP_STEP(v, 0x118);  // row_shr:8  -> lane15/31/47/63 = row sums
  v = DPP_STEP(v, 0x142);  // row_bcast:15
  v = DPP_STEP(v, 0x143);  // row_bcast:31 -> lane63 = wave sum
  return v;
}

__global__ __launch_bounds__(64)
void rnn_scan(const float* __restrict__ mw, const float* __restrict__ nw,
              float* __restrict__ out) {
  const int b = blockIdx.x;       // batch
  const int lane = threadIdx.x;   // 0..63
  const int base = lane * 8;      // this lane's 8 h indices

  float m0[8], m1[8], n0[8], n1[8], h[8];
  const float2* mp = (const float2*)mw;
  const float2* np = (const float2*)nw;
#pragma unroll
  for (int j = 0; j < 8; ++j) {
    float2 mm = mp[base + j];
    float2 nn = np[base + j];
    m0[j] = mm.x; m1[j] = mm.y;
    n0[j] = ALPHA * nn.x; n1[j] = ALPHA * nn.y;  // fold alpha into n
    h[j] = 0.f;
  }

  float* row = out + (size_t)b * 2048 * 512 + base;

  // prefetch xp row 0
  float4 xa = *(const float4*)(row);
  float4 xb = *(const float4*)(row + 4);

  for (int t = 0; t < 2048; ++t) {
    float xp0 = xa.x, xp1 = xa.y, xp2 = xa.z, xp3 = xa.w;
    float xp4 = xb.x, xp5 = xb.y, xp6 = xb.z, xp7 = xb.w;
    if (t < 2047) {  // prefetch next row (read-before-write of that row: safe)
      xa = *(const float4*)(row + (size_t)(t + 1) * 512);
      xb = *(const float4*)(row + (size_t)(t + 1) * 512 + 4);
    }
    float xp[8] = {xp0, xp1, xp2, xp3, xp4, xp5, xp6, xp7};

    // partials of s = tanh(h) . n  (alpha pre-folded)
    float p0 = 0.f, p1 = 0.f;
#pragma unroll
    for (int j = 0; j < 8; ++j) {
      float x = fminf(fmaxf(h[j], -3.f), 3.f);
      float u = x * x;
      float num = x * (27.f + u);                       // Pade 3/2 tanh
      float den = __builtin_amdgcn_rcpf(fmaf(9.f, u, 27.f));
      float th = num * den;
      p0 = fmaf(th, n0[j], p0);
      p1 = fmaf(th, n1[j], p1);
    }
    p0 = wave_sum63(p0);
    p1 = wave_sum63(p1);
    float s0 = __int_as_float(__builtin_amdgcn_readlane(__float_as_int(p0), 63));
    float s1 = __int_as_float(__builtin_amdgcn_readlane(__float_as_int(p1), 63));

#pragma unroll
    for (int j = 0; j < 8; ++j) {
      float bse = fmaf(1.f - ALPHA, h[j], ALPHA * xp[j]);
      h[j] = fmaf(s0, m0[j], fmaf(s1, m1[j], bse));
    }

    *(float4*)(row + (size_t)t * 512)     = make_float4(h[0], h[1], h[2], h[3]);
    *(float4*)(row + (size_t)t * 512 + 4) = make_float4(h[4], h[5], h[6], h[7]);
  }
}

// ------------------------------------------------------------- launcher ----
extern "C" void kernel_launch(void* const* d_in, const int* in_sizes, int n_in,
                              void* d_out, int out_size, void* d_ws, size_t ws_size,
                              hipStream_t stream) {
  const float* x  = (const float*)d_in[0];
  const float* mw = (const float*)d_in[1];
  const float* nw = (const float*)d_in[2];
  const float* Iw = (const float*)d_in[3];
  float* out = (float*)d_out;

  dim3 grid(65536 / BM, 512 / BN);           // 1024 x 8
  xproj_gemm<<<grid, 256, 0, stream>>>(x, Iw, out);
  rnn_scan<<<32, 64, 0, stream>>>(mw, nw, out);
}

// Round 2
// 665.972 us; speedup vs baseline: 2.1667x; 2.1667x over previous
//
#include <hip/hip_runtime.h>

// LowRankRNN: h' = (1-a)h + a*(tanh(h) @ J^T + xp),  J = m n^T (rank 2)
// Phase 1: xp = x @ I^T  (fp32 tiled GEMM, M=65536 N=512 K=128) -> written into d_out
// Phase 2: per-batch sequential scan, 1 wave/batch, h in registers,
//          rank-2 feedback via two DPP wave-reductions, in-place overwrite of d_out.
// R2 change: 8-deep register-ring prefetch of xp rows (was 1-deep) to hide
// ~900-cycle HBM load latency behind 8 steps of VALU chain.

#define ALPHA 0.1f

// ---------------------------------------------------------------- GEMM ----
#define BM 64
#define BN 64
#define BKK 32
#define LDT 72  // padded LDS row (floats), 16B-aligned groups

__global__ __launch_bounds__(256)
void xproj_gemm(const float* __restrict__ X, const float* __restrict__ Iw,
                float* __restrict__ C) {
  __shared__ float As[BKK * LDT];  // As[k][m]
  __shared__ float Bs[BKK * LDT];  // Bs[k][n]
  const int id = threadIdx.x;
  const int tx = id & 15;   // col group (4 cols)
  const int ty = id >> 4;   // row group (4 rows)
  const int kk = id & 31;   // staging k
  const int mg = id >> 5;   // staging row-group of 8
  const int m0 = blockIdx.x * BM;
  const int n0 = blockIdx.y * BN;

  float acc[4][4] = {};

  for (int k0 = 0; k0 < 128; k0 += BKK) {
    {
      const float* ga = X + (size_t)(m0 + mg * 8) * 128 + k0 + kk;
      float a0 = ga[0 * 128], a1 = ga[1 * 128], a2 = ga[2 * 128], a3 = ga[3 * 128];
      float a4 = ga[4 * 128], a5 = ga[5 * 128], a6 = ga[6 * 128], a7 = ga[7 * 128];
      float4* wa = (float4*)&As[kk * LDT + mg * 8];
      wa[0] = make_float4(a0, a1, a2, a3);
      wa[1] = make_float4(a4, a5, a6, a7);
      const float* gb = Iw + (size_t)(n0 + mg * 8) * 128 + k0 + kk;
      float b0 = gb[0 * 128], b1 = gb[1 * 128], b2 = gb[2 * 128], b3 = gb[3 * 128];
      float b4 = gb[4 * 128], b5 = gb[5 * 128], b6 = gb[6 * 128], b7 = gb[7 * 128];
      float4* wb = (float4*)&Bs[kk * LDT + mg * 8];
      wb[0] = make_float4(b0, b1, b2, b3);
      wb[1] = make_float4(b4, b5, b6, b7);
    }
    __syncthreads();
#pragma unroll
    for (int kb = 0; kb < BKK; ++kb) {
      float4 a = *(const float4*)&As[kb * LDT + ty * 4];
      float4 b = *(const float4*)&Bs[kb * LDT + tx * 4];
      float av[4] = {a.x, a.y, a.z, a.w};
      float bv[4] = {b.x, b.y, b.z, b.w};
#pragma unroll
      for (int i = 0; i < 4; ++i)
#pragma unroll
        for (int j = 0; j < 4; ++j) acc[i][j] = fmaf(av[i], bv[j], acc[i][j]);
    }
    __syncthreads();
  }

#pragma unroll
  for (int i = 0; i < 4; ++i) {
    float4 o = make_float4(acc[i][0], acc[i][1], acc[i][2], acc[i][3]);
    *(float4*)&C[(size_t)(m0 + ty * 4 + i) * 512 + n0 + tx * 4] = o;
  }
}

// ---------------------------------------------------------------- scan ----
#define DPP_STEP(v, ctrl)                                                     \
  ((v) + __int_as_float(__builtin_amdgcn_update_dpp(                          \
             0, __float_as_int(v), (ctrl), 0xf, 0xf, true)))

__device__ __forceinline__ float wave_sum63(float v) {
  v = DPP_STEP(v, 0x111);  // row_shr:1
  v = DPP_STEP(v, 0x112);  // row_shr:2
  v = DPP_STEP(v, 0x114);  // row_shr:4
  v = DPP_STEP(v, 0x118);  // row_shr:8
  v = DPP_STEP(v, 0x142);  // row_bcast:15
  v = DPP_STEP(v, 0x143);  // row_bcast:31 -> lane63 = wave sum
  return v;
}

#define PF 8  // prefetch depth (rows of xp in the register ring)

__global__ __launch_bounds__(64)
void rnn_scan(const float* __restrict__ mw, const float* __restrict__ nw,
              float* __restrict__ out) {
  const int b = blockIdx.x;       // batch
  const int lane = threadIdx.x;   // 0..63
  const int base = lane * 8;      // this lane's 8 h indices

  float m0[8], m1[8], n0[8], n1[8], h[8];
  const float2* mp = (const float2*)mw;
  const float2* np = (const float2*)nw;
#pragma unroll
  for (int j = 0; j < 8; ++j) {
    float2 mm = mp[base + j];
    float2 nn = np[base + j];
    m0[j] = mm.x; m1[j] = mm.y;
    n0[j] = ALPHA * nn.x; n1[j] = ALPHA * nn.y;  // fold alpha into n
    h[j] = 0.f;
  }

  float* row = out + (size_t)b * 2048 * 512 + base;

  // ring of PF prefetched xp rows (2 float4 each) — issued PF steps ahead
  float4 ra[PF], rb[PF];
#pragma unroll
  for (int i = 0; i < PF; ++i) {
    ra[i] = *(const float4*)(row + (size_t)i * 512);
    rb[i] = *(const float4*)(row + (size_t)i * 512 + 4);
  }

  // one scan step: consume ring slot u for time t; (optionally) refill slot
  // with row t+PF; compute; store h_t.
  auto step = [&](int t, int u, bool refill) {
    float4 xa = ra[u], xb = rb[u];   // waitcnt lands here: load is PF steps old
    if (refill) {
      ra[u] = *(const float4*)(row + (size_t)(t + PF) * 512);
      rb[u] = *(const float4*)(row + (size_t)(t + PF) * 512 + 4);
    }
    float xp[8] = {xa.x, xa.y, xa.z, xa.w, xb.x, xb.y, xb.z, xb.w};

    // s = alpha * (tanh(h) . n), two rank components, split accumulators
    float p0a = 0.f, p0b = 0.f, p1a = 0.f, p1b = 0.f;
#pragma unroll
    for (int j = 0; j < 4; ++j) {
      float x = fminf(fmaxf(h[j], -3.f), 3.f);
      float u2 = x * x;
      float th = (x * (27.f + u2)) * __builtin_amdgcn_rcpf(fmaf(9.f, u2, 27.f));
      p0a = fmaf(th, n0[j], p0a);
      p1a = fmaf(th, n1[j], p1a);
      float x2 = fminf(fmaxf(h[j + 4], -3.f), 3.f);
      float v2 = x2 * x2;
      float th2 = (x2 * (27.f + v2)) * __builtin_amdgcn_rcpf(fmaf(9.f, v2, 27.f));
      p0b = fmaf(th2, n0[j + 4], p0b);
      p1b = fmaf(th2, n1[j + 4], p1b);
    }
    float p0 = wave_sum63(p0a + p0b);
    float p1 = wave_sum63(p1a + p1b);
    float s0 = __int_as_float(__builtin_amdgcn_readlane(__float_as_int(p0), 63));
    float s1 = __int_as_float(__builtin_amdgcn_readlane(__float_as_int(p1), 63));

#pragma unroll
    for (int j = 0; j < 8; ++j) {
      float bse = fmaf(1.f - ALPHA, h[j], ALPHA * xp[j]);
      h[j] = fmaf(s0, m0[j], fmaf(s1, m1[j], bse));
    }

    *(float4*)(row + (size_t)t * 512)     = make_float4(h[0], h[1], h[2], h[3]);
    *(float4*)(row + (size_t)t * 512 + 4) = make_float4(h[4], h[5], h[6], h[7]);
  };

  // main: 2040 steps with refill, epilogue: last PF steps drain the ring
  for (int tb = 0; tb < 2048 - PF; tb += PF) {
#pragma unroll
    for (int u = 0; u < PF; ++u) step(tb + u, u, true);
  }
#pragma unroll
  for (int u = 0; u < PF; ++u) step(2048 - PF + u, u, false);
}

// ------------------------------------------------------------- launcher ----
extern "C" void kernel_launch(void* const* d_in, const int* in_sizes, int n_in,
                              void* d_out, int out_size, void* d_ws, size_t ws_size,
                              hipStream_t stream) {
  const float* x  = (const float*)d_in[0];
  const float* mw = (const float*)d_in[1];
  const float* nw = (const float*)d_in[2];
  const float* Iw = (const float*)d_in[3];
  float* out = (float*)d_out;

  dim3 grid(65536 / BM, 512 / BN);  // 1024 x 8
  xproj_gemm<<<grid, 256, 0, stream>>>(x, Iw, out);
  rnn_scan<<<32, 64, 0, stream>>>(mw, nw, out);
}